// Round 10
// baseline (787.105 us; speedup 1.0000x reference)
//
#include <hip/hip_runtime.h>
#include <hip/hip_bf16.h>
#include <math.h>

#define N_NODES 50000
#define N_EDGES 800000
#define D_NODE 64
#define D_EDGE 32
#define OUT_DIM 32
#define NUM_HEADS 4
#define NCH 49            // ceil(N_NODES/1024)

// ---- bf16 helpers (manual RNE pack, shift unpack) ----
__device__ __forceinline__ unsigned bf16rne(float x) {
    unsigned u = __float_as_uint(x);
    unsigned r = ((u >> 16) & 1u) + 0x7fffu;
    return (u + r) >> 16;
}
__device__ __forceinline__ float2 unpack_bf2(unsigned p) {
    return make_float2(__uint_as_float(p << 16), __uint_as_float(p & 0xffff0000u));
}

// ---- K0: detect attn_mask storage dtype (u8 / f32 / i32) ----
__global__ void k_detect(const unsigned char* __restrict__ mask, int* __restrict__ mode) {
    __shared__ int cnt;
    if (threadIdx.x == 0) cnt = 0;
    __syncthreads();
    int c = 0;
    for (int i = threadIdx.x; i < 4096; i += 256) c += (mask[i] != 0);
    atomicAdd(&cnt, c);
    __syncthreads();
    if (threadIdx.x == 0) {
        int md;
        if (cnt > (4096 * 70) / 100)      md = 0;  // uint8 bool
        else if (cnt > (4096 * 35) / 100) md = 1;  // float32
        else                              md = 2;  // int32
        *mode = md;
    }
}

__device__ __forceinline__ bool loadmask(const void* m, int mode, int e) {
    if (mode == 0) return ((const unsigned char*)m)[e] != 0;
    if (mode == 1) return ((const float*)m)[e] != 0.f;
    return ((const int*)m)[e] != 0;
}

// ---- K1: node precompute GEMM ----
// mb=0: Psrc (fp32) = nf @ Wa[0:64]
// mb=1: PT2[n][l].x (bf16x2) = (nf @ Wa[96:160]) dims 2l,2l+1   (tgt block of W_a)
// mb=2: PT2[n][l].y (bf16x2) = (nf @ Wm[32:96])  dims 2l,2l+1   (tgt block of W_m)
__global__ __launch_bounds__(256) void k_nodegemm(
    const float* __restrict__ nf, const float* __restrict__ Wa, const float* __restrict__ Wm,
    float* __restrict__ Psrc, unsigned* __restrict__ PT2) {
    __shared__ float At[64][72];
    __shared__ float Bt[64][128];
    const int mb = blockIdx.y;
    const float* Wsrc = (mb == 0) ? Wa : (mb == 1 ? (Wa + 96 * 128) : (Wm + 32 * 128));
    const int n0 = blockIdx.x * 64;
    const int tid = threadIdx.x;

    for (int i = tid; i < 1024; i += 256) {
        int r = i >> 4;
        int kc = (i & 15) << 2;
        float4 v = make_float4(0.f, 0.f, 0.f, 0.f);
        if (n0 + r < N_NODES) v = *(const float4*)(nf + (size_t)(n0 + r) * 64 + kc);
        At[kc + 0][r] = v.x; At[kc + 1][r] = v.y; At[kc + 2][r] = v.z; At[kc + 3][r] = v.w;
    }
    for (int i = tid; i < 2048; i += 256) {
        int k = i >> 5;
        int c = (i & 31) << 2;
        *(float4*)(&Bt[k][c]) = *(const float4*)(Wsrc + (size_t)k * 128 + c);
    }
    __syncthreads();

    const int ty = tid >> 5;
    const int tx = tid & 31;
    float acc[8][4];
#pragma unroll
    for (int r = 0; r < 8; r++)
#pragma unroll
        for (int c = 0; c < 4; c++) acc[r][c] = 0.f;

    for (int k = 0; k < 64; k++) {
        float4 b = *(const float4*)(&Bt[k][tx * 4]);
        float4 a0 = *(const float4*)(&At[k][ty * 8]);
        float4 a1 = *(const float4*)(&At[k][ty * 8 + 4]);
        float a[8] = {a0.x, a0.y, a0.z, a0.w, a1.x, a1.y, a1.z, a1.w};
#pragma unroll
        for (int r = 0; r < 8; r++) {
            acc[r][0] += a[r] * b.x; acc[r][1] += a[r] * b.y;
            acc[r][2] += a[r] * b.z; acc[r][3] += a[r] * b.w;
        }
    }
    for (int r = 0; r < 8; r++) {
        int n = n0 + ty * 8 + r;
        if (n >= N_NODES) continue;
        if (mb == 0) {
            *(float4*)(Psrc + (size_t)n * 128 + tx * 4) =
                make_float4(acc[r][0], acc[r][1], acc[r][2], acc[r][3]);
        } else {
            // lane-pair packing: PT2 is [N][64] uint2; this thread owns lanes 2tx, 2tx+1
            unsigned p0 = bf16rne(acc[r][0]) | (bf16rne(acc[r][1]) << 16);
            unsigned p1 = bf16rne(acc[r][2]) | (bf16rne(acc[r][3]) << 16);
            unsigned fld = (mb == 1) ? 0u : 1u;   // .x for Ptgta, .y for Ptgtm
            PT2[((size_t)n * 64 + 2 * tx) * 2 + fld] = p0;
            PT2[((size_t)n * 64 + 2 * tx + 1) * 2 + fld] = p1;
        }
    }
}

// ---- K2: degree count ----
__global__ void k_deg(const int* __restrict__ src, int* __restrict__ deg) {
    int i = blockIdx.x * blockDim.x + threadIdx.x;
    if (i < N_EDGES) atomicAdd(&deg[src[i]], 1);
}

// ---- K3a: per-1024-chunk sums ----
__global__ void k_scan_partial(const int* __restrict__ deg, int* __restrict__ csum) {
    __shared__ int sd[256];
    int b = blockIdx.x, tid = threadIdx.x;
    int s = 0, st = b * 1024;
    for (int i = tid; i < 1024; i += 256) {
        int idx = st + i;
        if (idx < N_NODES) s += deg[idx];
    }
    sd[tid] = s; __syncthreads();
    for (int off = 128; off > 0; off >>= 1) {
        if (tid < off) sd[tid] += sd[tid + off];
        __syncthreads();
    }
    if (tid == 0) csum[b] = sd[0];
}

// ---- K3b: exclusive scan of chunk sums ----
__global__ void k_scan_chunks(int* __restrict__ csum) {
    if (threadIdx.x == 0 && blockIdx.x == 0) {
        int acc = 0;
        for (int i = 0; i < NCH; i++) { int v = csum[i]; csum[i] = acc; acc += v; }
    }
}

// ---- K3c: in-chunk scan -> base offsets ----
__global__ __launch_bounds__(1024) void k_scan_apply(
    const int* __restrict__ deg, const int* __restrict__ csum, int* __restrict__ basep) {
    __shared__ int sd[1024];
    int b = blockIdx.x, tid = threadIdx.x;
    int idx = b * 1024 + tid;
    int v = (idx < N_NODES) ? deg[idx] : 0;
    sd[tid] = v; __syncthreads();
    for (int off = 1; off < 1024; off <<= 1) {
        int add = (tid >= off) ? sd[tid - off] : 0;
        __syncthreads();
        sd[tid] += add;
        __syncthreads();
    }
    if (idx < N_NODES) basep[idx] = csum[b] + sd[tid] - v;
}

// ---- K4: scatter edge ids into per-node buckets ----
__global__ void k_scatter(const int* __restrict__ src, const int* __restrict__ basep,
                          int* __restrict__ cursor, int* __restrict__ order) {
    int i = blockIdx.x * blockDim.x + threadIdx.x;
    if (i < N_EDGES) {
        int s = src[i];
        int p = basep[s] + atomicAdd(&cursor[s], 1);
        order[p] = i;
    }
}

// ---- K4b: build pre-resolved sorted streams ----
// tmE[p] = (e<<32) | (mask<<16) | tgt ; efS[p][k] = ef[e][k] (if DO_EFS)
template <bool DO_EFS>
__global__ void k_gather(const int* __restrict__ order, const int* __restrict__ tgt,
                         const void* __restrict__ mask, const int* __restrict__ modep,
                         const float* __restrict__ ef,
                         float* __restrict__ efS, unsigned long long* __restrict__ tmE) {
    const int g = threadIdx.x >> 5, k = threadIdx.x & 31;
    const int mode = *modep;
    const int p0 = (blockIdx.x * 8 + g) * 4;   // 25000 blocks * 8 groups * 4 = 800000
#pragma unroll
    for (int q = 0; q < 4; q++) {
        int p = p0 + q;
        int e = order[p];
        if (DO_EFS) efS[(size_t)p * 32 + k] = ef[(size_t)e * 32 + k];
        if (k == 0) {
            unsigned long long mk = loadmask(mask, mode, e) ? 1ull : 0ull;
            tmE[p] = ((unsigned long long)(unsigned)e << 32) | (mk << 16)
                   | (unsigned long long)(unsigned)tgt[e];
        }
    }
}

// ---- K5: fully fused per-node GATv2, deep-pipelined ----
// Wave per node over src-sorted streams. Lane l: head h=l>>4, dims (2l, 2l+1).
// Chain per edge: sequential tmE (3 ahead) -> one uint2 PT gather (2 ahead).
// No max pass: u = exp(min(logit,60)); masked -> 0; dead node <=> den==0 -> uniform fallback.
// Message GEMM factored out: sum_e u*(ef@Wm) == (sum_e u*ef)@Wm (per-node tail).
template <bool USE_EFS>
__global__ __launch_bounds__(256) void k_fused(
    const float* __restrict__ ef, const float* __restrict__ efS,
    const unsigned long long* __restrict__ tmE,
    const float* __restrict__ Wa, const float* __restrict__ Wm, const float* __restrict__ aw,
    const float* __restrict__ Psrc, const uint2* __restrict__ PT2,
    const int* __restrict__ deg, const int* __restrict__ basep,
    float* __restrict__ out) {
    const int lane = threadIdx.x & 63;
    const int wv = threadIdx.x >> 6;
    const int n = blockIdx.x * 4 + wv;          // exact: 12500*4 = 50000
    const int l15 = lane & 15;
    const int base16 = lane & 48;
    const int d0 = lane * 2;                    // global dims d0, d0+1 (same head)

    // W_a edge-block columns (d0,d0+1) in VGPRs
    float2 W[32];
#pragma unroll
    for (int j = 0; j < 32; j++)
        W[j] = *(const float2*)(Wa + (size_t)(64 + j) * 128 + d0);

    const float2 awv = *(const float2*)(aw + 2 * l15);
    const int dg = deg[n], bs = basep[n];
    const float2 ps = *(const float2*)(Psrc + (size_t)n * 128 + d0);

    float acc0 = 0.f, acc1 = 0.f;     // sum u * Ptgtm  (this lane's 2 dims)
    float w0 = 0.f, w1 = 0.f;         // sum u * ef     (this head, k = 2*l15, 2*l15+1)
    float den = 0.f;
    float accU0 = 0.f, accU1 = 0.f;   // uniform fallback (dead nodes)
    float wU0 = 0.f, wU1 = 0.f;

    const int last = N_EDGES - 1;
    // pipeline preload: tmE for i=0..2; PT for i=0,1; ef row for i=0
    unsigned long long tm0 = tmE[min(bs + 0, last)];
    unsigned long long tm1 = tmE[min(bs + 1, last)];
    unsigned long long tm2 = tmE[min(bs + 2, last)];
    uint2 pt0 = PT2[(size_t)(tm0 & 0xFFFFu) * 64 + lane];
    uint2 pt1 = PT2[(size_t)(tm1 & 0xFFFFu) * 64 + lane];
    float2 ef0;
    if (USE_EFS) ef0 = *(const float2*)(efS + (size_t)min(bs, last) * 32 + 2 * l15);
    else         ef0 = *(const float2*)(ef + (size_t)(tm0 >> 32) * 32 + 2 * l15);

    for (int i = 0; i < dg; i++) {
        // issue next-stage loads
        unsigned long long tm3 = tmE[min(bs + i + 3, last)];
        uint2 pt2 = PT2[(size_t)(tm2 & 0xFFFFu) * 64 + lane];
        float2 ef1;
        if (USE_EFS) ef1 = *(const float2*)(efS + (size_t)min(bs + i + 1, last) * 32 + 2 * l15);
        else         ef1 = *(const float2*)(ef + (size_t)(tm1 >> 32) * 32 + 2 * l15);

        // compute on edge i (pt0, ef0, mask from tm0)
        float2 paf = unpack_bf2(pt0.x);
        float a0 = ps.x + paf.x;
        float a1 = ps.y + paf.y;
#pragma unroll
        for (int j = 0; j < 32; j += 2) {
            int sl = base16 + (j >> 1);
            float ex = __shfl(ef0.x, sl);
            float ey = __shfl(ef0.y, sl);
            a0 += ex * W[j].x + ey * W[j + 1].x;
            a1 += ex * W[j].y + ey * W[j + 1].y;
        }
        float lr0 = (a0 >= 0.f) ? a0 : 0.2f * a0;
        float lr1 = (a1 >= 0.f) ? a1 : 0.2f * a1;
        float v = lr0 * awv.x + lr1 * awv.y;
        v += __shfl_xor(v, 8);
        v += __shfl_xor(v, 4);
        v += __shfl_xor(v, 2);
        v += __shfl_xor(v, 1);
        float u = ((tm0 >> 16) & 1ull) ? __expf(fminf(v, 60.f)) : 0.f;

        float2 pmf = unpack_bf2(pt0.y);
        acc0 += u * pmf.x; acc1 += u * pmf.y;
        w0 += u * ef0.x;   w1 += u * ef0.y;
        den += u;
        accU0 += pmf.x;    accU1 += pmf.y;
        wU0 += ef0.x;      wU1 += ef0.y;

        // rotate rings
        tm0 = tm1; tm1 = tm2; tm2 = tm3;
        pt0 = pt1; pt1 = pt2;
        ef0 = ef1;
    }

    // dead-node (all edges masked) -> uniform weights over all edges
    bool dead = (dg > 0) && (den == 0.f);
    float sw0 = dead ? wU0 : w0, sw1 = dead ? wU1 : w1;
    float sa0 = dead ? accU0 : acc0, sa1 = dead ? accU1 : acc1;
    float sden = dead ? (float)dg : den;

    // per-node tail: (sum u*ef) @ Wm_edge for dims d0, d0+1
    float t0 = 0.f, tt1 = 0.f;
#pragma unroll
    for (int k = 0; k < 32; k += 2) {
        int sl = base16 + (k >> 1);
        float wa = __shfl(sw0, sl);
        float wb = __shfl(sw1, sl);
        float2 m0 = *(const float2*)(Wm + (size_t)k * 128 + d0);
        float2 m1 = *(const float2*)(Wm + (size_t)(k + 1) * 128 + d0);
        t0  += wa * m0.x + wb * m1.x;
        tt1 += wa * m0.y + wb * m1.y;
    }
    float o0 = (dg > 0) ? (sa0 + t0) / sden : 0.f;
    float o1 = (dg > 0) ? (sa1 + tt1) / sden : 0.f;
    *(float2*)(out + (size_t)n * 128 + d0) = make_float2(o0, o1);
}

extern "C" void kernel_launch(void* const* d_in, const int* in_sizes, int n_in,
                              void* d_out, int out_size, void* d_ws, size_t ws_size,
                              hipStream_t stream) {
    const float* nf = (const float*)d_in[0];
    const float* ef = (const float*)d_in[1];
    const int* eidx = (const int*)d_in[2];
    const void* mask = d_in[3];
    const float* Wa = (const float*)d_in[4];
    const float* Wm = (const float*)d_in[5];
    const float* aw = (const float*)d_in[6];
    const int* src = eidx;
    const int* tgt = eidx + N_EDGES;
    float* out = (float*)d_out;

    char* ws = (char*)d_ws;
    size_t off = 0;
    auto alloc = [&](size_t bytes) -> void* {
        void* p = ws + off;
        off += (bytes + 255) & ~(size_t)255;
        return p;
    };
    int* mode       = (int*)alloc(256);
    float* Psrc     = (float*)alloc((size_t)N_NODES * 128 * 4);
    unsigned* PT2   = (unsigned*)alloc((size_t)N_NODES * 64 * 8);   // [N][64] uint2
    int* deg        = (int*)alloc((size_t)N_NODES * 4);
    int* cursor     = (int*)alloc((size_t)N_NODES * 4);
    int* basep      = (int*)alloc((size_t)N_NODES * 4);
    int* csum       = (int*)alloc((size_t)NCH * 4);
    int* order      = (int*)alloc((size_t)N_EDGES * 4);
    unsigned long long* tmE = (unsigned long long*)alloc((size_t)N_EDGES * 8);
    size_t base_need = off;
    float* efS      = (float*)alloc((size_t)N_EDGES * 32 * 4);      // 102.4 MB, optional
    const bool use_efs = (ws_size >= off);
    (void)base_need;

    hipMemsetAsync(deg, 0, (size_t)N_NODES * 4, stream);
    hipMemsetAsync(cursor, 0, (size_t)N_NODES * 4, stream);

    k_detect<<<1, 256, 0, stream>>>((const unsigned char*)mask, mode);
    k_nodegemm<<<dim3((N_NODES + 63) / 64, 3), 256, 0, stream>>>(nf, Wa, Wm, Psrc, PT2);
    k_deg<<<(N_EDGES + 255) / 256, 256, 0, stream>>>(src, deg);
    k_scan_partial<<<NCH, 256, 0, stream>>>(deg, csum);
    k_scan_chunks<<<1, 64, 0, stream>>>(csum);
    k_scan_apply<<<NCH, 1024, 0, stream>>>(deg, csum, basep);
    k_scatter<<<(N_EDGES + 255) / 256, 256, 0, stream>>>(src, basep, cursor, order);
    if (use_efs) {
        k_gather<true><<<N_EDGES / 32, 256, 0, stream>>>(order, tgt, mask, mode, ef, efS, tmE);
        k_fused<true><<<N_NODES / 4, 256, 0, stream>>>(ef, efS, tmE, Wa, Wm, aw,
                                                       Psrc, (const uint2*)PT2, deg, basep, out);
    } else {
        k_gather<false><<<N_EDGES / 32, 256, 0, stream>>>(order, tgt, mask, mode, ef, efS, tmE);
        k_fused<false><<<N_NODES / 4, 256, 0, stream>>>(ef, efS, tmE, Wa, Wm, aw,
                                                        Psrc, (const uint2*)PT2, deg, basep, out);
    }
}